// Round 14
// baseline (180.051 us; speedup 1.0000x reference)
//
#include <hip/hip_runtime.h>

#define NROWS 65536
#define DIM 64
#define KCODES 8192
#define DECAYF 0.99f
#define EPSV 1e-5f
#define KD (KCODES * DIM)
#define KSPLIT 4
#define KC (KCODES / KSPLIT)   // 2048 codes per split chunk
#define ROUNDS (KC / 128)      // 16 rounds x 128 codes (16 KB) per chunk

typedef _Float16 half8 __attribute__((ext_vector_type(8)));
typedef float f32x16 __attribute__((ext_vector_type(16)));

// ws layout (float offsets) — total ~4.0 MB
#define WS_STATS  0          // 256: mean[64], rstd[64], running_std[64]
#define WS_NHCK   256        // 8192: 10.6875 - ||e||^2/2 (centered, plain order)
#define WS_EBUF   8448       // 262144: 8192 codes x 64 dims f16 (1 MB)
#define WS_PSUM   270592     // 65536 TRANSPOSED: psumT[col*1024 + blk]
#define WS_PSQ    336128     // 65536 TRANSPOSED
#define WS_PACKED 401664     // 65536 u32
#define WS_DW     467200     // 524288
#define WS_COUNTS 991488     // 8192
// PACKED..COUNTS contiguous (598016 floats) zeroed by k_prep_stats
#define ZERO_F4   149504

// ---------------- K1: fused prep(emb) + colstats partial(x) + ws zeroing ---
// grid 1024 x 256 threads (1024-block grid: r13 tail win, ~12 us).
// ebuf layout (half8): idx = R*1024 + t*256 + c*64 + h*32 + col
//   code = R*128 + t*32 + col ; dims = c*16 + h*8 + j   (r8 layout)
// psum/psq written TRANSPOSED (col-major) so k_colstats_final reads coalesced.
__global__ __launch_bounds__(256) void k_prep_stats(
    const float* __restrict__ emb, const float* __restrict__ x,
    half8* __restrict__ ebuf, float* __restrict__ nhck,
    float* __restrict__ psumT, float* __restrict__ psqT,
    float4* __restrict__ zbase)
{
    const int tid = blockIdx.x * 256 + threadIdx.x;

    // ---- part C: zero packed+dw+counts ----
    if (tid < ZERO_F4) zbase[tid] = float4{0.f, 0.f, 0.f, 0.f};

    // ---- part A: emb -> f16 centered plane + nhck (first 256 blocks) ----
    if (tid < 65536) {
        const int code = tid >> 3, sub = tid & 7;
        const int c = sub >> 1, h = sub & 1;
        const float* e = emb + (size_t)code * DIM + c * 16 + h * 8;
        float4 a = *(const float4*)e;
        float4 b = *(const float4*)(e + 4);
        float f[8] = {a.x, a.y, a.z, a.w, b.x, b.y, b.z, b.w};
        half8 hh;
        float ssq = 0.f;
        #pragma unroll
        for (int i = 0; i < 8; ++i) {
            hh[i] = (_Float16)(f[i] - 0.5f);   // centered: halves f16 quant err
            ssq += f[i] * f[i];
        }
        #pragma unroll
        for (int o = 1; o < 8; o <<= 1) ssq += __shfl_xor(ssq, o, 64);
        // centered score bias keeps |score| small so the low-13-bit key
        // corruption (bfi-max trick) stays ~1e-3
        if (sub == 0) nhck[code] = 10.6875f - 0.5f * ssq;
        const int R = code >> 7, t = (code >> 5) & 3, col = code & 31;
        ebuf[(size_t)R * 1024 + t * 256 + c * 64 + h * 32 + col] = hh;
    }

    // ---- part B: column partial sums over 64 rows, transposed store ----
    {
        const int wave = threadIdx.x >> 6;
        const int col  = threadIdx.x & 63;
        const int base = blockIdx.x * 64;
        float s = 0.f, q = 0.f;
        #pragma unroll 4
        for (int i = 0; i < 16; ++i) {
            int r = base + i * 4 + wave;
            float v = x[(size_t)r * DIM + col];
            s += v;
            q += v * v;
        }
        __shared__ float ls[4][64];
        __shared__ float lq[4][64];
        ls[wave][col] = s;
        lq[wave][col] = q;
        __syncthreads();
        if (threadIdx.x < 64) {
            psumT[col * 1024 + blockIdx.x] = ls[0][col] + ls[1][col] + ls[2][col] + ls[3][col];
            psqT[col * 1024 + blockIdx.x]  = lq[0][col] + lq[1][col] + lq[2][col] + lq[3][col];
        }
    }
}

// ---------------- K1b: finalize stats — 64 blocks (one per column) ---------
__global__ __launch_bounds__(256) void k_colstats_final(
    const float* __restrict__ psumT, const float* __restrict__ psqT,
    float* __restrict__ stats)
{
    const int col = blockIdx.x, t = threadIdx.x;
    float4 a = *(const float4*)(psumT + col * 1024 + t * 4);
    float4 b = *(const float4*)(psqT + col * 1024 + t * 4);
    float s = a.x + a.y + a.z + a.w;
    float q = b.x + b.y + b.z + b.w;
    __shared__ float rs[256], rq[256];
    rs[t] = s; rq[t] = q;
    __syncthreads();
    if (t < 128) { rs[t] += rs[t + 128]; rq[t] += rq[t + 128]; }
    __syncthreads();
    if (t < 64) {
        s = rs[t] + rs[t + 64];
        q = rq[t] + rq[t + 64];
        #pragma unroll
        for (int o = 32; o > 0; o >>= 1) {
            s += __shfl_xor(s, o, 64);
            q += __shfl_xor(q, o, 64);
        }
        if (t == 0) {
            const float n = (float)NROWS;
            float mean = s / n;
            float var = q / n - mean * mean;
            if (var < 0.f) var = 0.f;
            stats[col]       = mean;
            stats[64 + col]  = 1.0f / sqrtf(var + EPSV);
            stats[128 + col] = sqrtf(var * (n / (n - 1.0f)) + EPSV);
        }
    }
}

// ---------------- K3: 32x32 MFMA distance argmin, 64 rows/wave -------------
// r12-verbatim (best measured config: 98.4 us). 256 thr = 4 waves; wave owns
// 64 rows (two 32-row tiles sharing B frags); block = 256 rows x KC codes;
// grid = (NROWS/256, KSPLIT). Single f16 plane, LDS dbuf gload_lds staging.
// Maximizes w = f16(xn).f16(e-0.5) + nhck' (== argmin dist, score centered).
// Select: bfi-max — low 13 mantissa bits of best carry key = 8191-code
// (larger key = smaller code wins ties for w>=0).
__device__ __forceinline__ void gload16(const void* g, void* l)
{
    __builtin_amdgcn_global_load_lds(
        (const __attribute__((address_space(1))) void*)g,
        (__attribute__((address_space(3))) void*)l, 16, 0, 0);
}

__device__ __forceinline__ void build_afrag(const float* __restrict__ xr,
                                            const float* __restrict__ stats,
                                            int h, half8* a)
{
    #pragma unroll
    for (int c = 0; c < 4; ++c) {
        const int d = c * 16 + h * 8;
        float4 v0 = *(const float4*)(xr + d);
        float4 v1 = *(const float4*)(xr + d + 4);
        float4 m0 = *(const float4*)(stats + d);
        float4 m1 = *(const float4*)(stats + d + 4);
        float4 s0 = *(const float4*)(stats + 64 + d);
        float4 s1 = *(const float4*)(stats + 64 + d + 4);
        a[c][0] = (_Float16)((v0.x - m0.x) * s0.x);
        a[c][1] = (_Float16)((v0.y - m0.y) * s0.y);
        a[c][2] = (_Float16)((v0.z - m0.z) * s0.z);
        a[c][3] = (_Float16)((v0.w - m0.w) * s0.w);
        a[c][4] = (_Float16)((v1.x - m1.x) * s1.x);
        a[c][5] = (_Float16)((v1.y - m1.y) * s1.y);
        a[c][6] = (_Float16)((v1.z - m1.z) * s1.z);
        a[c][7] = (_Float16)((v1.w - m1.w) * s1.w);
    }
}

__global__ __launch_bounds__(256) void k_argmin32(
    const float* __restrict__ x, const half8* __restrict__ ebuf,
    const float* __restrict__ nhckg, const float* __restrict__ stats,
    unsigned* __restrict__ packed)
{
    __shared__ half8 smem[2048];   // 32 KB: 2 x 16 KB rounds

    const int lane = threadIdx.x & 63;
    const int wave = threadIdx.x >> 6;
    const int kc = blockIdx.y;
    const int col = lane & 31, h = lane >> 5;
    const int rowbase = blockIdx.x * 256 + wave * 64;

    // ---- A fragments for the two row-tiles ----
    half8 a0[4], a1[4];
    build_afrag(x + (size_t)(rowbase + col) * DIM, stats, h, a0);
    build_afrag(x + (size_t)(rowbase + 32 + col) * DIM, stats, h, a1);

    float best0[16], best1[16];
    #pragma unroll
    for (int i = 0; i < 16; ++i) { best0[i] = -3.4e38f; best1[i] = -3.4e38f; }

    const half8* esrc = ebuf + (size_t)kc * (KC * 8);   // 8 half8 per code
    const float* ckb = nhckg + kc * KC;

    // prologue stage (256 thr x 16 B x 4 = 16 KB) + first-round nhck prefetch
    {
        const char* src = (const char*)esrc + threadIdx.x * 16;
        char* dst = (char*)smem + threadIdx.x * 16;
        #pragma unroll
        for (int i = 0; i < 4; ++i) gload16(src + i * 4096, dst + i * 4096);
    }
    float nv[4];
    #pragma unroll
    for (int t = 0; t < 4; ++t) nv[t] = ckb[t * 32 + col];
    __syncthreads();

    for (int R = 0; R < ROUNDS; ++R) {
        const int buf = R & 1;
        float nvn[4] = {0.f, 0.f, 0.f, 0.f};
        if (R < ROUNDS - 1) {
            const char* src = (const char*)esrc + (size_t)(R + 1) * 16384 + threadIdx.x * 16;
            char* dst = (char*)smem + (buf ^ 1) * 16384 + threadIdx.x * 16;
            #pragma unroll
            for (int i = 0; i < 4; ++i) gload16(src + i * 4096, dst + i * 4096);
            #pragma unroll
            for (int t = 0; t < 4; ++t) nvn[t] = ckb[(R + 1) * 128 + t * 32 + col];
        }

        const half8* sb = smem + buf * 1024 + lane;
        #pragma unroll
        for (int t = 0; t < 4; ++t) {
            half8 b0 = sb[t * 256];
            half8 b1 = sb[t * 256 + 64];
            half8 b2 = sb[t * 256 + 128];
            half8 b3 = sb[t * 256 + 192];
            f32x16 acc0, acc1;
            #pragma unroll
            for (int i = 0; i < 16; ++i) { acc0[i] = nv[t]; acc1[i] = nv[t]; }
            __builtin_amdgcn_s_setprio(1);
            acc0 = __builtin_amdgcn_mfma_f32_32x32x16_f16(a0[0], b0, acc0, 0, 0, 0);
            acc1 = __builtin_amdgcn_mfma_f32_32x32x16_f16(a1[0], b0, acc1, 0, 0, 0);
            acc0 = __builtin_amdgcn_mfma_f32_32x32x16_f16(a0[1], b1, acc0, 0, 0, 0);
            acc1 = __builtin_amdgcn_mfma_f32_32x32x16_f16(a1[1], b1, acc1, 0, 0, 0);
            acc0 = __builtin_amdgcn_mfma_f32_32x32x16_f16(a0[2], b2, acc0, 0, 0, 0);
            acc1 = __builtin_amdgcn_mfma_f32_32x32x16_f16(a1[2], b2, acc1, 0, 0, 0);
            acc0 = __builtin_amdgcn_mfma_f32_32x32x16_f16(a0[3], b3, acc0, 0, 0, 0);
            acc1 = __builtin_amdgcn_mfma_f32_32x32x16_f16(a1[3], b3, acc1, 0, 0, 0);
            __builtin_amdgcn_s_setprio(0);
            // key = 8191 - global code for this lane's column
            const unsigned key = (unsigned)(8191 - (kc * KC + R * 128 + t * 32 + col));
            #pragma unroll
            for (int i = 0; i < 16; ++i) {
                unsigned u0 = (__float_as_uint(acc0[i]) & 0xFFFFE000u) | key;
                best0[i] = fmaxf(best0[i], __uint_as_float(u0));
                unsigned u1 = (__float_as_uint(acc1[i]) & 0xFFFFE000u) | key;
                best1[i] = fmaxf(best1[i], __uint_as_float(u1));
            }
        }
        __syncthreads();
        #pragma unroll
        for (int t = 0; t < 4; ++t) nv[t] = nvn[t];
    }

    // cross-lane max over the 32 code columns (keys break ties -> no equals)
    #pragma unroll
    for (int off = 1; off < 32; off <<= 1) {
        #pragma unroll
        for (int i = 0; i < 16; ++i) {
            best0[i] = fmaxf(best0[i], __shfl_xor(best0[i], off, 64));
            best1[i] = fmaxf(best1[i], __shfl_xor(best1[i], off, 64));
        }
    }
    // publish per-row winner as sortable u32; atomicMax merges KSPLIT chunks.
    if (col == 0) {
        const int rb = rowbase + 4 * h;
        #pragma unroll
        for (int i = 0; i < 16; ++i) {
            int row = rb + (i & 3) + 8 * (i >> 2);
            unsigned u0 = __float_as_uint(best0[i]);
            u0 = (u0 & 0x80000000u) ? ~u0 : (u0 | 0x80000000u);
            atomicMax(&packed[row], u0);
            unsigned u1 = __float_as_uint(best1[i]);
            u1 = (u1 & 0x80000000u) ? ~u1 : (u1 | 0x80000000u);
            atomicMax(&packed[row + 32], u1);
        }
    }
}

// ---------------- K4: scatter (segment sums) + counts, float2/thread -------
__global__ __launch_bounds__(256) void k_scatter(
    const float* __restrict__ x, const float* __restrict__ stats,
    const unsigned* __restrict__ packed,
    float* __restrict__ dw, float* __restrict__ counts)
{
    const int t = blockIdx.x * 256 + threadIdx.x;   // over NROWS*32
    const int row = t >> 5, c2 = (t & 31) * 2;
    const unsigned v = packed[row];
    const unsigned key = (v & 0x80000000u) ? (v & 8191u) : (~v & 8191u);
    const int j = 8191 - (int)key;
    float2 xv = *(const float2*)(x + (size_t)row * DIM + c2);
    float2 mu = *(const float2*)(stats + c2);
    float2 sg = *(const float2*)(stats + 64 + c2);
    atomicAdd(&dw[(size_t)j * DIM + c2],     (xv.x - mu.x) * sg.x);
    atomicAdd(&dw[(size_t)j * DIM + c2 + 1], (xv.y - mu.y) * sg.y);
    if (c2 == 0) atomicAdd(&counts[j], 1.0f);
}

// ---------------- K5: epilogue ----------------
__global__ __launch_bounds__(256) void k_final(
    const float* __restrict__ emb, const float* __restrict__ cs,
    const float* __restrict__ dw, const float* __restrict__ counts,
    const float* __restrict__ stats, float* __restrict__ out)
{
    const int t = blockIdx.x * 256 + threadIdx.x; // over K*D
    const int k = t >> 6, d = t & 63;
    float csk = cs[k];
    float ns = csk * DECAYF + (1.f - DECAYF) * counts[k];
    float ne = (csk * emb[t] * DECAYF + (1.f - DECAYF) * dw[t]) / ns;
    out[KD + t] = ne;
    out[t] = ne * stats[128 + d] + stats[d];
    if (d == 0) out[2 * KD + k] = ns;
}

extern "C" void kernel_launch(void* const* d_in, const int* in_sizes, int n_in,
                              void* d_out, int out_size, void* d_ws, size_t ws_size,
                              hipStream_t stream)
{
    const float* x   = (const float*)d_in[0];
    const float* emb = (const float*)d_in[1];
    const float* cs  = (const float*)d_in[2];
    float* out = (float*)d_out;
    float* ws  = (float*)d_ws;

    float* stats  = ws + WS_STATS;
    float* nhck   = ws + WS_NHCK;
    half8* ebuf   = (half8*)(ws + WS_EBUF);
    float* psumT  = ws + WS_PSUM;
    float* psqT   = ws + WS_PSQ;
    unsigned* packed = (unsigned*)(ws + WS_PACKED);
    float* dw     = ws + WS_DW;
    float* counts = ws + WS_COUNTS;

    k_prep_stats<<<1024, 256, 0, stream>>>(emb, x, ebuf, nhck, psumT, psqT,
                                           (float4*)(ws + WS_PACKED));
    k_colstats_final<<<64, 256, 0, stream>>>(psumT, psqT, stats);
    dim3 g3(NROWS / 256, KSPLIT);
    k_argmin32<<<g3, 256, 0, stream>>>(x, ebuf, nhck, stats, packed);
    k_scatter<<<NROWS * 32 / 256, 256, 0, stream>>>(x, stats, packed, dw, counts);
    k_final<<<KD / 256, 256, 0, stream>>>(emb, cs, dw, counts, stats, out);
}

// Round 15
// 146.635 us; speedup vs baseline: 1.2279x; 1.2279x over previous
//
#include <hip/hip_runtime.h>

#define NROWS 65536
#define DIM 64
#define KCODES 8192
#define DECAYF 0.99f
#define EPSV 1e-5f
#define KD (KCODES * DIM)
#define KSPLIT 4
#define KC (KCODES / KSPLIT)   // 2048 codes per split chunk
#define ROUNDS (KC / 128)      // 16 rounds x 128 codes (16 KB) per chunk

typedef _Float16 half8 __attribute__((ext_vector_type(8)));
typedef float f32x16 __attribute__((ext_vector_type(16)));

// ws layout (float offsets) — total ~4.0 MB
#define WS_STATS  0          // 256: mean[64], rstd[64], running_std[64]
#define WS_NHCK   256        // 8192: 10.6875 - ||e||^2/2 (centered)
#define WS_EBUF   8448       // 262144: 8192 codes x 64 dims f16 (1 MB)
#define WS_PSUM   270592     // 65536: psum[blk*64 + col] (coalesced store)
#define WS_PSQ    336128     // 65536
#define WS_PACKED 401664     // 65536 u32
#define WS_DW     467200     // 524288
#define WS_COUNTS 991488     // 8192
// PACKED..COUNTS contiguous (598016 floats) zeroed by k_prep_stats
#define ZERO_F4   149504

// ---------------- K1: fused prep(emb) + colstats partial(x) + ws zeroing ---
// grid 1024 x 256 threads (1024-block grid: r13 tail win).
// ebuf layout (half8): idx = R*1024 + t*256 + c*64 + h*32 + col
//   code = R*128 + t*32 + col ; dims = c*16 + h*8 + j   (r8 layout)
// psum stored NORMAL layout (r14's transposed store was 64 scattered scalar
// stores/block — regressed; coalesced 64-lane store here).
__global__ __launch_bounds__(256) void k_prep_stats(
    const float* __restrict__ emb, const float* __restrict__ x,
    half8* __restrict__ ebuf, float* __restrict__ nhck,
    float* __restrict__ psum, float* __restrict__ psq,
    float4* __restrict__ zbase)
{
    const int tid = blockIdx.x * 256 + threadIdx.x;

    // ---- part C: zero packed+dw+counts ----
    if (tid < ZERO_F4) zbase[tid] = float4{0.f, 0.f, 0.f, 0.f};

    // ---- part A: emb -> f16 centered plane + nhck (first 256 blocks) ----
    if (tid < 65536) {
        const int code = tid >> 3, sub = tid & 7;
        const int c = sub >> 1, h = sub & 1;
        const float* e = emb + (size_t)code * DIM + c * 16 + h * 8;
        float4 a = *(const float4*)e;
        float4 b = *(const float4*)(e + 4);
        float f[8] = {a.x, a.y, a.z, a.w, b.x, b.y, b.z, b.w};
        half8 hh;
        float ssq = 0.f;
        #pragma unroll
        for (int i = 0; i < 8; ++i) {
            hh[i] = (_Float16)(f[i] - 0.5f);   // centered: halves f16 quant err
            ssq += f[i] * f[i];
        }
        #pragma unroll
        for (int o = 1; o < 8; o <<= 1) ssq += __shfl_xor(ssq, o, 64);
        // centered score bias keeps |score| small so the low-13-bit key
        // corruption (bfi-max trick) stays ~1e-3
        if (sub == 0) nhck[code] = 10.6875f - 0.5f * ssq;
        const int R = code >> 7, t = (code >> 5) & 3, col = code & 31;
        ebuf[(size_t)R * 1024 + t * 256 + c * 64 + h * 32 + col] = hh;
    }

    // ---- part B: column partial sums over 64 rows, coalesced store ----
    {
        const int wave = threadIdx.x >> 6;
        const int col  = threadIdx.x & 63;
        const int base = blockIdx.x * 64;
        float s = 0.f, q = 0.f;
        #pragma unroll 4
        for (int i = 0; i < 16; ++i) {
            int r = base + i * 4 + wave;
            float v = x[(size_t)r * DIM + col];
            s += v;
            q += v * v;
        }
        __shared__ float ls[4][64];
        __shared__ float lq[4][64];
        ls[wave][col] = s;
        lq[wave][col] = q;
        __syncthreads();
        if (threadIdx.x < 64) {
            psum[blockIdx.x * 64 + col] = ls[0][col] + ls[1][col] + ls[2][col] + ls[3][col];
            psq[blockIdx.x * 64 + col]  = lq[0][col] + lq[1][col] + lq[2][col] + lq[3][col];
        }
    }
}

// ---------------- K1b: finalize stats — 64 blocks (one per column) ---------
// Strided reads (psum[i*64+col]) are uncoalesced but issued by 16K parallel
// threads — latency-hidden, unlike the old serial 1-block loop.
__global__ __launch_bounds__(256) void k_colstats_final(
    const float* __restrict__ psum, const float* __restrict__ psq,
    float* __restrict__ stats)
{
    const int col = blockIdx.x, t = threadIdx.x;
    float s = 0.f, q = 0.f;
    #pragma unroll
    for (int i = 0; i < 4; ++i) {
        s += psum[(t + i * 256) * 64 + col];
        q += psq[(t + i * 256) * 64 + col];
    }
    __shared__ float rs[256], rq[256];
    rs[t] = s; rq[t] = q;
    __syncthreads();
    if (t < 128) { rs[t] += rs[t + 128]; rq[t] += rq[t + 128]; }
    __syncthreads();
    if (t < 64) {
        s = rs[t] + rs[t + 64];
        q = rq[t] + rq[t + 64];
        #pragma unroll
        for (int o = 32; o > 0; o >>= 1) {
            s += __shfl_xor(s, o, 64);
            q += __shfl_xor(q, o, 64);
        }
        if (t == 0) {
            const float n = (float)NROWS;
            float mean = s / n;
            float var = q / n - mean * mean;
            if (var < 0.f) var = 0.f;
            stats[col]       = mean;
            stats[64 + col]  = 1.0f / sqrtf(var + EPSV);
            stats[128 + col] = sqrtf(var * (n / (n - 1.0f)) + EPSV);
        }
    }
}

// ---------------- K3: 32x32 MFMA distance argmin, 64 rows/wave -------------
// r12-verbatim (98.4/98.5 us measured twice). 256 thr = 4 waves; wave owns
// 64 rows (two 32-row tiles sharing B frags); block = 256 rows x KC codes;
// grid = (NROWS/256, KSPLIT). Single f16 plane, LDS dbuf gload_lds staging.
// Maximizes w = f16(xn).f16(e-0.5) + nhck' (== argmin dist, score centered).
// Select: bfi-max — low 13 mantissa bits of best carry key = 8191-code
// (larger key = smaller code wins ties for w>=0).
__device__ __forceinline__ void gload16(const void* g, void* l)
{
    __builtin_amdgcn_global_load_lds(
        (const __attribute__((address_space(1))) void*)g,
        (__attribute__((address_space(3))) void*)l, 16, 0, 0);
}

__device__ __forceinline__ void build_afrag(const float* __restrict__ xr,
                                            const float* __restrict__ stats,
                                            int h, half8* a)
{
    #pragma unroll
    for (int c = 0; c < 4; ++c) {
        const int d = c * 16 + h * 8;
        float4 v0 = *(const float4*)(xr + d);
        float4 v1 = *(const float4*)(xr + d + 4);
        float4 m0 = *(const float4*)(stats + d);
        float4 m1 = *(const float4*)(stats + d + 4);
        float4 s0 = *(const float4*)(stats + 64 + d);
        float4 s1 = *(const float4*)(stats + 64 + d + 4);
        a[c][0] = (_Float16)((v0.x - m0.x) * s0.x);
        a[c][1] = (_Float16)((v0.y - m0.y) * s0.y);
        a[c][2] = (_Float16)((v0.z - m0.z) * s0.z);
        a[c][3] = (_Float16)((v0.w - m0.w) * s0.w);
        a[c][4] = (_Float16)((v1.x - m1.x) * s1.x);
        a[c][5] = (_Float16)((v1.y - m1.y) * s1.y);
        a[c][6] = (_Float16)((v1.z - m1.z) * s1.z);
        a[c][7] = (_Float16)((v1.w - m1.w) * s1.w);
    }
}

__global__ __launch_bounds__(256) void k_argmin32(
    const float* __restrict__ x, const half8* __restrict__ ebuf,
    const float* __restrict__ nhckg, const float* __restrict__ stats,
    unsigned* __restrict__ packed)
{
    __shared__ half8 smem[2048];   // 32 KB: 2 x 16 KB rounds

    const int lane = threadIdx.x & 63;
    const int wave = threadIdx.x >> 6;
    const int kc = blockIdx.y;
    const int col = lane & 31, h = lane >> 5;
    const int rowbase = blockIdx.x * 256 + wave * 64;

    // ---- A fragments for the two row-tiles ----
    half8 a0[4], a1[4];
    build_afrag(x + (size_t)(rowbase + col) * DIM, stats, h, a0);
    build_afrag(x + (size_t)(rowbase + 32 + col) * DIM, stats, h, a1);

    float best0[16], best1[16];
    #pragma unroll
    for (int i = 0; i < 16; ++i) { best0[i] = -3.4e38f; best1[i] = -3.4e38f; }

    const half8* esrc = ebuf + (size_t)kc * (KC * 8);   // 8 half8 per code
    const float* ckb = nhckg + kc * KC;

    // prologue stage (256 thr x 16 B x 4 = 16 KB) + first-round nhck prefetch
    {
        const char* src = (const char*)esrc + threadIdx.x * 16;
        char* dst = (char*)smem + threadIdx.x * 16;
        #pragma unroll
        for (int i = 0; i < 4; ++i) gload16(src + i * 4096, dst + i * 4096);
    }
    float nv[4];
    #pragma unroll
    for (int t = 0; t < 4; ++t) nv[t] = ckb[t * 32 + col];
    __syncthreads();

    for (int R = 0; R < ROUNDS; ++R) {
        const int buf = R & 1;
        float nvn[4] = {0.f, 0.f, 0.f, 0.f};
        if (R < ROUNDS - 1) {
            const char* src = (const char*)esrc + (size_t)(R + 1) * 16384 + threadIdx.x * 16;
            char* dst = (char*)smem + (buf ^ 1) * 16384 + threadIdx.x * 16;
            #pragma unroll
            for (int i = 0; i < 4; ++i) gload16(src + i * 4096, dst + i * 4096);
            #pragma unroll
            for (int t = 0; t < 4; ++t) nvn[t] = ckb[(R + 1) * 128 + t * 32 + col];
        }

        const half8* sb = smem + buf * 1024 + lane;
        #pragma unroll
        for (int t = 0; t < 4; ++t) {
            half8 b0 = sb[t * 256];
            half8 b1 = sb[t * 256 + 64];
            half8 b2 = sb[t * 256 + 128];
            half8 b3 = sb[t * 256 + 192];
            f32x16 acc0, acc1;
            #pragma unroll
            for (int i = 0; i < 16; ++i) { acc0[i] = nv[t]; acc1[i] = nv[t]; }
            __builtin_amdgcn_s_setprio(1);
            acc0 = __builtin_amdgcn_mfma_f32_32x32x16_f16(a0[0], b0, acc0, 0, 0, 0);
            acc1 = __builtin_amdgcn_mfma_f32_32x32x16_f16(a1[0], b0, acc1, 0, 0, 0);
            acc0 = __builtin_amdgcn_mfma_f32_32x32x16_f16(a0[1], b1, acc0, 0, 0, 0);
            acc1 = __builtin_amdgcn_mfma_f32_32x32x16_f16(a1[1], b1, acc1, 0, 0, 0);
            acc0 = __builtin_amdgcn_mfma_f32_32x32x16_f16(a0[2], b2, acc0, 0, 0, 0);
            acc1 = __builtin_amdgcn_mfma_f32_32x32x16_f16(a1[2], b2, acc1, 0, 0, 0);
            acc0 = __builtin_amdgcn_mfma_f32_32x32x16_f16(a0[3], b3, acc0, 0, 0, 0);
            acc1 = __builtin_amdgcn_mfma_f32_32x32x16_f16(a1[3], b3, acc1, 0, 0, 0);
            __builtin_amdgcn_s_setprio(0);
            // key = 8191 - global code for this lane's column
            const unsigned key = (unsigned)(8191 - (kc * KC + R * 128 + t * 32 + col));
            #pragma unroll
            for (int i = 0; i < 16; ++i) {
                unsigned u0 = (__float_as_uint(acc0[i]) & 0xFFFFE000u) | key;
                best0[i] = fmaxf(best0[i], __uint_as_float(u0));
                unsigned u1 = (__float_as_uint(acc1[i]) & 0xFFFFE000u) | key;
                best1[i] = fmaxf(best1[i], __uint_as_float(u1));
            }
        }
        __syncthreads();
        #pragma unroll
        for (int t = 0; t < 4; ++t) nv[t] = nvn[t];
    }

    // cross-lane max over the 32 code columns (keys break ties -> no equals)
    #pragma unroll
    for (int off = 1; off < 32; off <<= 1) {
        #pragma unroll
        for (int i = 0; i < 16; ++i) {
            best0[i] = fmaxf(best0[i], __shfl_xor(best0[i], off, 64));
            best1[i] = fmaxf(best1[i], __shfl_xor(best1[i], off, 64));
        }
    }
    // publish per-row winner as sortable u32; atomicMax merges KSPLIT chunks.
    if (col == 0) {
        const int rb = rowbase + 4 * h;
        #pragma unroll
        for (int i = 0; i < 16; ++i) {
            int row = rb + (i & 3) + 8 * (i >> 2);
            unsigned u0 = __float_as_uint(best0[i]);
            u0 = (u0 & 0x80000000u) ? ~u0 : (u0 | 0x80000000u);
            atomicMax(&packed[row], u0);
            unsigned u1 = __float_as_uint(best1[i]);
            u1 = (u1 & 0x80000000u) ? ~u1 : (u1 | 0x80000000u);
            atomicMax(&packed[row + 32], u1);
        }
    }
}

// ---------------- K4: scatter (segment sums) + counts ----------------
// r13 form: 1 float/thread — a wave's 64 lanes hit 64 CONTIGUOUS dw words
// of one code (optimal atomic shape). r14's float2 (stride-2 per atomic
// instruction) doubled the L2 atomic transactions and regressed ~20 us.
__global__ __launch_bounds__(256) void k_scatter(
    const float* __restrict__ x, const float* __restrict__ stats,
    const unsigned* __restrict__ packed,
    float* __restrict__ dw, float* __restrict__ counts)
{
    const int t = blockIdx.x * 256 + threadIdx.x;
    const int row = t >> 6, col = t & 63;
    const unsigned v = packed[row];
    const unsigned key = (v & 0x80000000u) ? (v & 8191u) : (~v & 8191u);
    const int j = 8191 - (int)key;
    float xv = (x[(size_t)row * DIM + col] - stats[col]) * stats[64 + col];
    atomicAdd(&dw[(size_t)j * DIM + col], xv);
    if (col == 0) atomicAdd(&counts[j], 1.0f);
}

// ---------------- K5: epilogue ----------------
__global__ __launch_bounds__(256) void k_final(
    const float* __restrict__ emb, const float* __restrict__ cs,
    const float* __restrict__ dw, const float* __restrict__ counts,
    const float* __restrict__ stats, float* __restrict__ out)
{
    const int t = blockIdx.x * 256 + threadIdx.x; // over K*D
    const int k = t >> 6, d = t & 63;
    float csk = cs[k];
    float ns = csk * DECAYF + (1.f - DECAYF) * counts[k];
    float ne = (csk * emb[t] * DECAYF + (1.f - DECAYF) * dw[t]) / ns;
    out[KD + t] = ne;
    out[t] = ne * stats[128 + d] + stats[d];
    if (d == 0) out[2 * KD + k] = ns;
}

extern "C" void kernel_launch(void* const* d_in, const int* in_sizes, int n_in,
                              void* d_out, int out_size, void* d_ws, size_t ws_size,
                              hipStream_t stream)
{
    const float* x   = (const float*)d_in[0];
    const float* emb = (const float*)d_in[1];
    const float* cs  = (const float*)d_in[2];
    float* out = (float*)d_out;
    float* ws  = (float*)d_ws;

    float* stats  = ws + WS_STATS;
    float* nhck   = ws + WS_NHCK;
    half8* ebuf   = (half8*)(ws + WS_EBUF);
    float* psum   = ws + WS_PSUM;
    float* psq    = ws + WS_PSQ;
    unsigned* packed = (unsigned*)(ws + WS_PACKED);
    float* dw     = ws + WS_DW;
    float* counts = ws + WS_COUNTS;

    k_prep_stats<<<1024, 256, 0, stream>>>(emb, x, ebuf, nhck, psum, psq,
                                           (float4*)(ws + WS_PACKED));
    k_colstats_final<<<64, 256, 0, stream>>>(psum, psq, stats);
    dim3 g3(NROWS / 256, KSPLIT);
    k_argmin32<<<g3, 256, 0, stream>>>(x, ebuf, nhck, stats, packed);
    k_scatter<<<(NROWS * DIM) / 256, 256, 0, stream>>>(x, stats, packed, dw, counts);
    k_final<<<KD / 256, 256, 0, stream>>>(emb, cs, dw, counts, stats, out);
}